// Round 1
// baseline (1569.004 us; speedup 1.0000x reference)
//
#include <hip/hip_runtime.h>

typedef unsigned short u16;
typedef float f32x4 __attribute__((ext_vector_type(4)));
typedef short short8 __attribute__((ext_vector_type(8)));

#define QK_SCALE_F 10.0f

__device__ __forceinline__ u16 f2b(float f) {
  union { float f; unsigned u; } c; c.f = f;
  return (u16)((c.u + 0x7fffu + ((c.u >> 16) & 1u)) >> 16);
}

__device__ __forceinline__ float wred_sum(float v) {
#pragma unroll
  for (int m = 32; m > 0; m >>= 1) v += __shfl_xor(v, m, 64);
  return v;
}
__device__ __forceinline__ float wred_max(float v) {
#pragma unroll
  for (int m = 32; m > 0; m >>= 1) v = fmaxf(v, __shfl_xor(v, m, 64));
  return v;
}

// ---------------------------------------------------------------------------
// Generic bf16 MFMA GEMM:  C[M,N] = A[M,K] * B^T[N,K]   (both bf16, row-major)
// 128x128 tile, BK=64, 256 threads = 4 waves (2x2), each wave 64x64 via 4x4
// v_mfma_f32_16x16x32_bf16 fragments. LDS XOR-swizzled (G4) for b128 reads.
// EPI 0: C fp32 = acc
// EPI 2: C bf16 = gelu(acc + P1[z][col]) * P2[row][z]      (hid GEMM)
// EPI 3: C fp32 = acc + P1[row*ldc+col]                     (moe combine)
// ---------------------------------------------------------------------------
#define BM 128
#define BN 128
#define BKK 64

template<int EPI>
__global__ __launch_bounds__(256)
void gemm_bt(const u16* __restrict__ A, const u16* __restrict__ B, void* __restrict__ Cv,
             int M, int N, int K, int lda, int ldb, int ldc,
             long zA, long zB, long zC,
             const float* __restrict__ P1, long zP1, const float* __restrict__ P2,
             int causal) {
  int z = blockIdx.z;
  int row0 = blockIdx.y * BM;
  int col0 = blockIdx.x * BN;
  if (causal && col0 > row0 + (BM - 1)) return;  // tile fully above causal diag
  A += zA * z; B += zB * z;
  int tid = threadIdx.x;
  int wave = tid >> 6, lane = tid & 63;
  int wm = wave >> 1, wn = wave & 1;

  __shared__ __align__(16) u16 lA[BM * BKK];
  __shared__ __align__(16) u16 lB[BN * BKK];

  f32x4 acc[4][4];
  f32x4 zf = {0.f, 0.f, 0.f, 0.f};
#pragma unroll
  for (int i = 0; i < 4; i++)
#pragma unroll
    for (int j = 0; j < 4; j++) acc[i][j] = zf;

  for (int k0 = 0; k0 < K; k0 += BKK) {
    __syncthreads();
    // stage A,B tiles: 1024 chunks of 8 bf16 each per tile; XOR-swizzle bank fix
#pragma unroll
    for (int i = 0; i < 4; i++) {
      int chunk = tid + (i << 8);
      int r = chunk >> 3, c8 = chunk & 7;
      short8 va = *(const short8*)(A + (long)(row0 + r) * lda + k0 + (c8 << 3));
      *(short8*)((char*)lA + ((r << 7) | ((c8 << 4) ^ ((r & 7) << 4)))) = va;
      short8 vb = *(const short8*)(B + (long)(col0 + r) * ldb + k0 + (c8 << 3));
      *(short8*)((char*)lB + ((r << 7) | ((c8 << 4) ^ ((r & 7) << 4)))) = vb;
    }
    __syncthreads();
#pragma unroll
    for (int kk = 0; kk < 2; kk++) {
      short8 af[4], bfr[4];
      int cb = (kk << 6) | ((lane >> 4) << 4);
#pragma unroll
      for (int mi = 0; mi < 4; mi++) {
        int R = (wm << 6) + (mi << 4) + (lane & 15);
        af[mi] = *(const short8*)((const char*)lA + ((R << 7) | (cb ^ ((R & 7) << 4))));
      }
#pragma unroll
      for (int nj = 0; nj < 4; nj++) {
        int R = (wn << 6) + (nj << 4) + (lane & 15);
        bfr[nj] = *(const short8*)((const char*)lB + ((R << 7) | (cb ^ ((R & 7) << 4))));
      }
#pragma unroll
      for (int mi = 0; mi < 4; mi++)
#pragma unroll
        for (int nj = 0; nj < 4; nj++)
          acc[mi][nj] = __builtin_amdgcn_mfma_f32_16x16x32_bf16(af[mi], bfr[nj], acc[mi][nj], 0, 0, 0);
    }
  }

#pragma unroll
  for (int mi = 0; mi < 4; mi++) {
#pragma unroll
    for (int nj = 0; nj < 4; nj++) {
#pragma unroll
      for (int rr = 0; rr < 4; rr++) {
        int row = row0 + (wm << 6) + (mi << 4) + ((lane >> 4) << 2) + rr;
        int col = col0 + (wn << 6) + (nj << 4) + (lane & 15);
        if (col < N) {
          float v = acc[mi][nj][rr];
          long cidx = zC * z + (long)row * ldc + col;
          if (EPI == 0) {
            ((float*)Cv)[cidx] = v;
          } else if (EPI == 2) {
            float t = v + P1[zP1 * z + col];
            float gl = 0.5f * t * (1.f + tanhf(0.7978845608f * (t + 0.044715f * t * t * t)));
            ((u16*)Cv)[cidx] = f2b(gl * P2[((long)row << 3) + z]);
          } else {  // EPI == 3
            ((float*)Cv)[cidx] = v + P1[(long)row * ldc + col];
          }
        }
      }
    }
  }
}

// fp32 [R][C] -> bf16 [C][R] tiled transpose-cast (weights -> B^T form)
__global__ __launch_bounds__(256)
void transpose_cast(const float* __restrict__ src, u16* __restrict__ dst,
                    int R, int C, long sz, long dz) {
  int z = blockIdx.z;
  src += sz * z; dst += dz * z;
  __shared__ float t[32][33];
  int c0 = blockIdx.x * 32, r0 = blockIdx.y * 32;
  int tx = threadIdx.x & 31, ty = threadIdx.x >> 5;
#pragma unroll
  for (int j = 0; j < 4; j++) {
    int r = ty + j * 8;
    t[r][tx] = src[(long)(r0 + r) * C + c0 + tx];
  }
  __syncthreads();
#pragma unroll
  for (int j = 0; j < 4; j++) {
    int r = ty + j * 8;
    dst[(long)(c0 + r) * R + r0 + tx] = f2b(t[tx][r]);
  }
}

// LayerNorm over D=1024, one row per block; optional fp32 and bf16 outputs
__global__ __launch_bounds__(256)
void ln_kernel(const float* __restrict__ x, const float* __restrict__ g,
               const float* __restrict__ b, float* __restrict__ yf, u16* __restrict__ yb) {
  int tid = threadIdx.x;
  long base = (long)blockIdx.x << 10;
  float4 v = *(const float4*)&x[base + tid * 4];
  float s = v.x + v.y + v.z + v.w;
  float q = v.x * v.x + v.y * v.y + v.z * v.z + v.w * v.w;
  s = wred_sum(s); q = wred_sum(q);
  __shared__ float2 red[4];
  int wave = tid >> 6, lane = tid & 63;
  if (lane == 0) red[wave] = make_float2(s, q);
  __syncthreads();
  float S1 = red[0].x + red[1].x + red[2].x + red[3].x;
  float S2 = red[0].y + red[1].y + red[2].y + red[3].y;
  float mu = S1 * (1.f / 1024.f);
  float var = S2 * (1.f / 1024.f) - mu * mu;
  float rs = rsqrtf(var + 1e-5f);
  float4 gv = *(const float4*)&g[tid * 4];
  float4 bv = *(const float4*)&b[tid * 4];
  float4 o;
  o.x = (v.x - mu) * rs * gv.x + bv.x;
  o.y = (v.y - mu) * rs * gv.y + bv.y;
  o.z = (v.z - mu) * rs * gv.z + bv.z;
  o.w = (v.w - mu) * rs * gv.w + bv.w;
  if (yf) *(float4*)&yf[base + tid * 4] = o;
  if (yb) {
    ushort4 ob; ob.x = f2b(o.x); ob.y = f2b(o.y); ob.z = f2b(o.z); ob.w = f2b(o.w);
    *(ushort4*)&yb[base + tid * 4] = ob;
  }
}

// l2norm+scale over DH=64 per (b,s,h); src [b][s][h*64+d] fp32 -> dst [b][h][s][d] bf16
__global__ __launch_bounds__(256)
void l2norm_kernel(const float* __restrict__ src, const float* __restrict__ scale, u16* __restrict__ dst) {
  int r = blockIdx.x * 4 + (threadIdx.x >> 6);
  int lane = threadIdx.x & 63;
  float v = src[((long)r << 6) + lane];
  float ss = v * v;
#pragma unroll
  for (int m = 32; m > 0; m >>= 1) ss += __shfl_xor(ss, m, 64);
  int h = r & 15, sIdx = (r >> 4) & 1023, b = r >> 14;
  float o = v * rsqrtf(ss + 1e-12f) * scale[(h << 6) + lane];
  dst[((((long)(b * 16 + h)) << 10) + sIdx) * 64 + lane] = f2b(o);
}

// V fp32 [b][s][h*64+d] -> V^T bf16 [z=(b,h)][128 (d, padded)][s]
__global__ __launch_bounds__(256)
void v_transpose(const float* __restrict__ vf, u16* __restrict__ vT) {
  int z = blockIdx.x, b = z >> 4, h = z & 15, s0 = blockIdx.y * 16;
  __shared__ u16 t[64][17];
  int si = threadIdx.x >> 6, d = threadIdx.x & 63;
#pragma unroll
  for (int j = 0; j < 4; j++) {
    int sl = j * 4 + si;
    t[d][sl] = f2b(vf[((long)(b << 10) + (s0 + sl)) * 1024 + (h << 6) + d]);
  }
  __syncthreads();
  int d2 = threadIdx.x >> 2, sj = threadIdx.x & 3;
#pragma unroll
  for (int j = 0; j < 4; j++) {
    int sl = j * 4 + sj;
    vT[((long)(z * 128 + d2) << 10) + s0 + sl] = t[d2][sl];
  }
}

// causal row softmax: logits fp32 [z][i][j] (*10) -> P bf16, zeros for j>i
__global__ __launch_bounds__(256)
void softmax_kernel(const float* __restrict__ logits, u16* __restrict__ P) {
  int i = blockIdx.x, z = blockIdx.y, tid = threadIdx.x;
  long base = ((long)z << 20) + ((long)i << 10);
  int len = i + 1;
  float lv[4];
  float mx = -1e30f;
  int cnt = 0;
  for (int j = tid; j < len; j += 256) { float l = logits[base + j] * QK_SCALE_F; lv[cnt++] = l; mx = fmaxf(mx, l); }
  mx = wred_max(mx);
  __shared__ float red[4];
  int wave = tid >> 6, lane = tid & 63;
  if (lane == 0) red[wave] = mx;
  __syncthreads();
  mx = fmaxf(fmaxf(red[0], red[1]), fmaxf(red[2], red[3]));
  float s = 0.f;
  for (int c = 0; c < cnt; c++) { lv[c] = __expf(lv[c] - mx); s += lv[c]; }
  s = wred_sum(s);
  __syncthreads();
  if (lane == 0) red[wave] = s;
  __syncthreads();
  s = red[0] + red[1] + red[2] + red[3];
  float inv = 1.f / s;
  cnt = 0;
  for (int j = tid; j < len; j += 256) P[base + j] = f2b(lv[cnt++] * inv);
  for (int j = tid; j < 1024; j += 256) if (j >= len) P[base + j] = 0;
}

// pv fp32 [z=(b,h)][i][d] -> acat bf16 [b][i][h*64+d]
__global__ __launch_bounds__(256)
void attn_cat_kernel(const float* __restrict__ pv, u16* __restrict__ acat) {
  int blk = blockIdx.x; int b = blk >> 10, i = blk & 1023;
#pragma unroll
  for (int j = 0; j < 4; ++j) {
    int col = threadIdx.x + j * 256;
    int h = col >> 6, d = col & 63;
    float v = pv[(((long)(b * 16 + h)) << 16) + (i << 6) + d];
    acat[((long)blk << 10) + col] = f2b(v);
  }
}

// gate = softmax(h2 @ gate_w + gate_b), one row per block
__global__ __launch_bounds__(256)
void gate_kernel(const float* __restrict__ h2, const float* __restrict__ gw,
                 const float* __restrict__ gb, float* __restrict__ gate) {
  int row = blockIdx.x, tid = threadIdx.x;
  const float* hr = h2 + ((long)row << 10);
  float acc[8];
#pragma unroll
  for (int e = 0; e < 8; e++) acc[e] = 0.f;
  for (int d = tid; d < 1024; d += 256) {
    float hv = hr[d];
    const float4* wp = (const float4*)&gw[d * 8];
    float4 w0 = wp[0], w1v = wp[1];
    acc[0] += hv * w0.x;  acc[1] += hv * w0.y;  acc[2] += hv * w0.z;  acc[3] += hv * w0.w;
    acc[4] += hv * w1v.x; acc[5] += hv * w1v.y; acc[6] += hv * w1v.z; acc[7] += hv * w1v.w;
  }
  __shared__ float red[8][4];
  int wave = tid >> 6, lane = tid & 63;
#pragma unroll
  for (int e = 0; e < 8; e++) { float v = wred_sum(acc[e]); if (lane == 0) red[e][wave] = v; }
  __syncthreads();
  if (tid == 0) {
    float l[8]; float mx = -1e30f;
    for (int e = 0; e < 8; e++) { l[e] = red[e][0] + red[e][1] + red[e][2] + red[e][3] + gb[e]; mx = fmaxf(mx, l[e]); }
    float s = 0.f;
    for (int e = 0; e < 8; e++) { l[e] = __expf(l[e] - mx); s += l[e]; }
    float inv = 1.f / s;
    for (int e = 0; e < 8; e++) gate[row * 8 + e] = l[e] * inv;
  }
}

// moe init: moe[row][d] = sum_e gate[row][e] * b2[e][d]
__global__ __launch_bounds__(256)
void bias_moe_kernel(const float* __restrict__ gate, const float* __restrict__ b2, float* __restrict__ moe) {
  int row = blockIdx.x, tid = threadIdx.x;
  __shared__ float gs[8];
  if (tid < 8) gs[tid] = gate[row * 8 + tid];
  __syncthreads();
  for (int col = tid; col < 1024; col += 256) {
    float s = 0.f;
#pragma unroll
    for (int e = 0; e < 8; e++) s += gs[e] * b2[(e << 10) + col];
    moe[((long)row << 10) + col] = s;
  }
}

extern "C" void kernel_launch(void* const* d_in, const int* in_sizes, int n_in,
                              void* d_out, int out_size, void* d_ws, size_t ws_size,
                              hipStream_t stream) {
  const float* x   = (const float*)d_in[0];
  const float* lng = (const float*)d_in[1];
  const float* lnb = (const float*)d_in[2];
  const float* Wq  = (const float*)d_in[3];
  const float* Wk  = (const float*)d_in[4];
  const float* Wv  = (const float*)d_in[5];
  const float* qs  = (const float*)d_in[6];
  const float* ks  = (const float*)d_in[7];
  const float* Wo  = (const float*)d_in[8];
  const float* gw  = (const float*)d_in[9];
  const float* gb  = (const float*)d_in[10];
  const float* w1  = (const float*)d_in[11];
  const float* b1  = (const float*)d_in[12];
  const float* w2  = (const float*)d_in[13];
  const float* b2  = (const float*)d_in[14];
  float* out = (float*)d_out;

  char* base = (char*)d_ws;
  size_t off = 0;
  auto alloc = [&](size_t bytes) { void* p = base + off; off = (off + bytes + 255) & ~(size_t)255; return p; };

  u16*   W1T  = (u16*)alloc(8l * 1024 * 4096 * 2);   // [e][4096][1024] (B^T per expert)
  u16*   W2T  = (u16*)alloc(1024l * 32768 * 2);      // [1024][32768]
  u16*   WQT  = (u16*)alloc(1024l * 1024 * 2);
  u16*   WKT  = (u16*)alloc(1024l * 1024 * 2);
  u16*   WVT  = (u16*)alloc(1024l * 1024 * 2);
  u16*   WOT  = (u16*)alloc(1024l * 1024 * 2);
  u16*   HB   = (u16*)alloc(2048l * 1024 * 2);       // LN1 out bf16
  float* QF   = (float*)alloc(2048l * 1024 * 4);
  float* KF   = (float*)alloc(2048l * 1024 * 4);
  float* VF   = (float*)alloc(2048l * 1024 * 4);
  u16*   QN   = (u16*)alloc(2048l * 1024 * 2);       // [b][h][s][d]
  u16*   KN   = (u16*)alloc(2048l * 1024 * 2);
  u16*   VT   = (u16*)alloc(32l * 128 * 1024 * 2);   // [z][128 pad][s]
  float* LOG  = (float*)alloc(32l * 1024 * 1024 * 4);// logits; region reused as HID bf16
  u16*   P    = (u16*)alloc(32l * 1024 * 1024 * 2);
  float* PV   = (float*)alloc(32l * 1024 * 64 * 4);
  u16*   ACAT = (u16*)alloc(2048l * 1024 * 2);
  float* APROJ= (float*)alloc(2048l * 1024 * 4);
  float* H2F  = (float*)alloc(2048l * 1024 * 4);
  u16*   H2B  = (u16*)alloc(2048l * 1024 * 2);
  float* GATE = (float*)alloc(2048l * 8 * 4);
  float* MOE  = (float*)alloc(2048l * 1024 * 4);
  u16*   HID  = (u16*)LOG;                           // [2048][32768] bf16, reuse

  if (off > ws_size) return;  // ws too small -> visible as stub-like failure

  dim3 blk(256);

  // weight prep (B^T bf16)
  transpose_cast<<<dim3(32, 32, 1), blk, 0, stream>>>(Wq, WQT, 1024, 1024, 0, 0);
  transpose_cast<<<dim3(32, 32, 1), blk, 0, stream>>>(Wk, WKT, 1024, 1024, 0, 0);
  transpose_cast<<<dim3(32, 32, 1), blk, 0, stream>>>(Wv, WVT, 1024, 1024, 0, 0);
  transpose_cast<<<dim3(32, 32, 1), blk, 0, stream>>>(Wo, WOT, 1024, 1024, 0, 0);
  transpose_cast<<<dim3(128, 32, 8), blk, 0, stream>>>(w1, W1T, 1024, 4096, 1024l * 4096, 4096l * 1024);
  transpose_cast<<<dim3(32, 1024, 1), blk, 0, stream>>>(w2, W2T, 32768, 1024, 0, 0);

  // LN1 -> h (bf16)
  ln_kernel<<<2048, blk, 0, stream>>>(x, lng, lnb, nullptr, HB);

  // QKV projections
  gemm_bt<0><<<dim3(8, 16, 1), blk, 0, stream>>>(HB, WQT, QF, 2048, 1024, 1024, 1024, 1024, 1024, 0, 0, 0, nullptr, 0, nullptr, 0);
  gemm_bt<0><<<dim3(8, 16, 1), blk, 0, stream>>>(HB, WKT, KF, 2048, 1024, 1024, 1024, 1024, 1024, 0, 0, 0, nullptr, 0, nullptr, 0);
  gemm_bt<0><<<dim3(8, 16, 1), blk, 0, stream>>>(HB, WVT, VF, 2048, 1024, 1024, 1024, 1024, 1024, 0, 0, 0, nullptr, 0, nullptr, 0);

  // l2norm + scale -> [b][h][s][d] bf16; V -> V^T
  l2norm_kernel<<<8192, blk, 0, stream>>>(QF, qs, QN);
  l2norm_kernel<<<8192, blk, 0, stream>>>(KF, ks, KN);
  v_transpose<<<dim3(32, 64, 1), blk, 0, stream>>>(VF, VT);

  // attention: QK^T (causal skip) -> softmax -> PV
  gemm_bt<0><<<dim3(8, 8, 32), blk, 0, stream>>>(QN, KN, LOG, 1024, 1024, 64, 64, 64, 1024,
                                                 65536, 65536, 1048576, nullptr, 0, nullptr, 1);
  softmax_kernel<<<dim3(1024, 32, 1), blk, 0, stream>>>(LOG, P);
  gemm_bt<0><<<dim3(1, 8, 32), blk, 0, stream>>>(P, VT, PV, 1024, 64, 1024, 1024, 1024, 64,
                                                 1048576, 131072, 65536, nullptr, 0, nullptr, 0);
  attn_cat_kernel<<<2048, blk, 0, stream>>>(PV, ACAT);

  // output projection + LN2
  gemm_bt<0><<<dim3(8, 16, 1), blk, 0, stream>>>(ACAT, WOT, APROJ, 2048, 1024, 1024, 1024, 1024, 1024, 0, 0, 0, nullptr, 0, nullptr, 0);
  ln_kernel<<<2048, blk, 0, stream>>>(APROJ, lng, lnb, H2F, H2B);

  // MoE: gate, hid = gelu(h2@w1+b1)*gate  (bf16, [2048][32768]), combine K=32768
  gate_kernel<<<2048, blk, 0, stream>>>(H2F, gw, gb, GATE);
  gemm_bt<2><<<dim3(32, 16, 8), blk, 0, stream>>>(H2B, W1T, HID, 2048, 4096, 1024, 1024, 1024, 32768,
                                                  0, 4096l * 1024, 4096, b1, 4096, GATE, 0);
  bias_moe_kernel<<<2048, blk, 0, stream>>>(GATE, b2, MOE);
  gemm_bt<3><<<dim3(8, 16, 1), blk, 0, stream>>>(HID, W2T, MOE, 2048, 1024, 32768, 32768, 32768, 1024,
                                                 0, 0, 0, MOE, 0, nullptr, 0);

  // final LN -> out
  ln_kernel<<<2048, blk, 0, stream>>>(MOE, lng, lnb, out, nullptr);
}

// Round 2
// 1052.974 us; speedup vs baseline: 1.4901x; 1.4901x over previous
//
#include <hip/hip_runtime.h>

typedef unsigned short u16;
typedef float f32x4 __attribute__((ext_vector_type(4)));
typedef short short8 __attribute__((ext_vector_type(8)));

#define QK_SCALE_F 10.0f

// async global->LDS, 16B per lane; LDS dest is wave-uniform base + lane*16
#define GLD_LDS(g, l) __builtin_amdgcn_global_load_lds( \
    (const __attribute__((address_space(1))) unsigned int*)(g), \
    (__attribute__((address_space(3))) unsigned int*)(l), 16, 0, 0)

__device__ __forceinline__ u16 f2b(float f) {
  union { float f; unsigned u; } c; c.f = f;
  return (u16)((c.u + 0x7fffu + ((c.u >> 16) & 1u)) >> 16);
}

__device__ __forceinline__ float wred_sum(float v) {
#pragma unroll
  for (int m = 32; m > 0; m >>= 1) v += __shfl_xor(v, m, 64);
  return v;
}
__device__ __forceinline__ float wred_max(float v) {
#pragma unroll
  for (int m = 32; m > 0; m >>= 1) v = fmaxf(v, __shfl_xor(v, m, 64));
  return v;
}

// ---------------------------------------------------------------------------
// Generic bf16 MFMA GEMM:  C[M,N] = A[M,K] * B^T[N,K]   (both bf16, row-major)
// 128x128 tile, BK=64, 256 threads = 4 waves (2x2), each wave 64x64 via 4x4
// v_mfma_f32_16x16x32_bf16 fragments.
// Staging: global_load_lds dwordx4, LINEAR LDS dest; XOR swizzle applied to
// the per-lane GLOBAL source column so the swizzled b128 read path (0 bank
// conflicts, verified R1) sees identical LDS content (rule 21).
// EPI 0: C fp32 = acc
// EPI 2: C bf16 = gelu(acc + P1[z][col]) * P2[row][z]      (hid GEMM)
// EPI 4: atomicAdd(C fp32, acc)                            (split-K combine)
// ---------------------------------------------------------------------------
#define BM 128
#define BN 128
#define BKK 64

template<int EPI>
__global__ __launch_bounds__(256)
void gemm_bt(const u16* __restrict__ A, const u16* __restrict__ B, void* __restrict__ Cv,
             int M, int N, int K, int lda, int ldb, int ldc,
             long zA, long zB, long zC,
             const float* __restrict__ P1, long zP1, const float* __restrict__ P2,
             int causal) {
  int z = blockIdx.z;
  int row0 = blockIdx.y * BM;
  int col0 = blockIdx.x * BN;
  if (causal && col0 > row0 + (BM - 1)) return;  // tile fully above causal diag
  A += zA * z; B += zB * z;
  int tid = threadIdx.x;
  int wave = tid >> 6, lane = tid & 63;
  int wm = wave >> 1, wn = wave & 1;

  __shared__ __align__(16) u16 lA[BM * BKK];
  __shared__ __align__(16) u16 lB[BN * BKK];

  f32x4 acc[4][4];
  f32x4 zf = {0.f, 0.f, 0.f, 0.f};
#pragma unroll
  for (int i = 0; i < 4; i++)
#pragma unroll
    for (int j = 0; j < 4; j++) acc[i][j] = zf;

  // per-lane staging geometry (constant across K loop)
  int l3 = lane >> 3;                       // 0..7  == row-within-8 == r&7
  int scol = ((lane & 7) ^ l3) << 3;        // swizzled source column (elements)
  long aoff[4], boff[4];
  int cbase[4];
#pragma unroll
  for (int i = 0; i < 4; i++) {
    int c = (wave << 2) + i;                // 1KB chunk id 0..15
    int r = (c << 3) + l3;                  // tile row 0..127
    aoff[i] = (long)(row0 + r) * lda + scol;
    boff[i] = (long)(col0 + r) * ldb + scol;
    cbase[i] = c << 10;                     // LDS byte offset of chunk
  }

  for (int k0 = 0; k0 < K; k0 += BKK) {
    __syncthreads();
#pragma unroll
    for (int i = 0; i < 4; i++) {
      GLD_LDS(A + aoff[i] + k0, (char*)lA + cbase[i]);
      GLD_LDS(B + boff[i] + k0, (char*)lB + cbase[i]);
    }
    __syncthreads();
#pragma unroll
    for (int kk = 0; kk < 2; kk++) {
      short8 af[4], bfr[4];
      int cb = (kk << 6) | ((lane >> 4) << 4);
#pragma unroll
      for (int mi = 0; mi < 4; mi++) {
        int R = (wm << 6) + (mi << 4) + (lane & 15);
        af[mi] = *(const short8*)((const char*)lA + ((R << 7) | (cb ^ ((R & 7) << 4))));
      }
#pragma unroll
      for (int nj = 0; nj < 4; nj++) {
        int R = (wn << 6) + (nj << 4) + (lane & 15);
        bfr[nj] = *(const short8*)((const char*)lB + ((R << 7) | (cb ^ ((R & 7) << 4))));
      }
#pragma unroll
      for (int mi = 0; mi < 4; mi++)
#pragma unroll
        for (int nj = 0; nj < 4; nj++)
          acc[mi][nj] = __builtin_amdgcn_mfma_f32_16x16x32_bf16(af[mi], bfr[nj], acc[mi][nj], 0, 0, 0);
    }
  }

#pragma unroll
  for (int mi = 0; mi < 4; mi++) {
#pragma unroll
    for (int nj = 0; nj < 4; nj++) {
#pragma unroll
      for (int rr = 0; rr < 4; rr++) {
        int row = row0 + (wm << 6) + (mi << 4) + ((lane >> 4) << 2) + rr;
        int col = col0 + (wn << 6) + (nj << 4) + (lane & 15);
        if (col < N) {
          float v = acc[mi][nj][rr];
          long cidx = zC * z + (long)row * ldc + col;
          if (EPI == 0) {
            ((float*)Cv)[cidx] = v;
          } else if (EPI == 2) {
            float t = v + P1[zP1 * z + col];
            float gl = 0.5f * t * (1.f + tanhf(0.7978845608f * (t + 0.044715f * t * t * t)));
            ((u16*)Cv)[cidx] = f2b(gl * P2[((long)row << 3) + z]);
          } else if (EPI == 4) {
            atomicAdd(&((float*)Cv)[cidx], v);
          }
        }
      }
    }
  }
}

// fp32 [R][C] -> bf16 [C][R] tiled transpose-cast (weights -> B^T form)
__global__ __launch_bounds__(256)
void transpose_cast(const float* __restrict__ src, u16* __restrict__ dst,
                    int R, int C, long sz, long dz) {
  int z = blockIdx.z;
  src += sz * z; dst += dz * z;
  __shared__ float t[32][33];
  int c0 = blockIdx.x * 32, r0 = blockIdx.y * 32;
  int tx = threadIdx.x & 31, ty = threadIdx.x >> 5;
#pragma unroll
  for (int j = 0; j < 4; j++) {
    int r = ty + j * 8;
    t[r][tx] = src[(long)(r0 + r) * C + c0 + tx];
  }
  __syncthreads();
#pragma unroll
  for (int j = 0; j < 4; j++) {
    int r = ty + j * 8;
    dst[(long)(c0 + r) * R + r0 + tx] = f2b(t[tx][r]);
  }
}

// LayerNorm over D=1024, one row per block; optional fp32 and bf16 outputs
__global__ __launch_bounds__(256)
void ln_kernel(const float* __restrict__ x, const float* __restrict__ g,
               const float* __restrict__ b, float* __restrict__ yf, u16* __restrict__ yb) {
  int tid = threadIdx.x;
  long base = (long)blockIdx.x << 10;
  float4 v = *(const float4*)&x[base + tid * 4];
  float s = v.x + v.y + v.z + v.w;
  float q = v.x * v.x + v.y * v.y + v.z * v.z + v.w * v.w;
  s = wred_sum(s); q = wred_sum(q);
  __shared__ float2 red[4];
  int wave = tid >> 6, lane = tid & 63;
  if (lane == 0) red[wave] = make_float2(s, q);
  __syncthreads();
  float S1 = red[0].x + red[1].x + red[2].x + red[3].x;
  float S2 = red[0].y + red[1].y + red[2].y + red[3].y;
  float mu = S1 * (1.f / 1024.f);
  float var = S2 * (1.f / 1024.f) - mu * mu;
  float rs = rsqrtf(var + 1e-5f);
  float4 gv = *(const float4*)&g[tid * 4];
  float4 bv = *(const float4*)&b[tid * 4];
  float4 o;
  o.x = (v.x - mu) * rs * gv.x + bv.x;
  o.y = (v.y - mu) * rs * gv.y + bv.y;
  o.z = (v.z - mu) * rs * gv.z + bv.z;
  o.w = (v.w - mu) * rs * gv.w + bv.w;
  if (yf) *(float4*)&yf[base + tid * 4] = o;
  if (yb) {
    ushort4 ob; ob.x = f2b(o.x); ob.y = f2b(o.y); ob.z = f2b(o.z); ob.w = f2b(o.w);
    *(ushort4*)&yb[base + tid * 4] = ob;
  }
}

// l2norm+scale over DH=64 per (b,s,h); src fp32 row (b*1024+s), col off+h*64+d
// -> dst [b][h][s][d] bf16
__global__ __launch_bounds__(256)
void l2norm_kernel(const float* __restrict__ src, const float* __restrict__ scale,
                   u16* __restrict__ dst, int ld, int off) {
  int r = blockIdx.x * 4 + (threadIdx.x >> 6);
  int lane = threadIdx.x & 63;
  float v = src[(long)(r >> 4) * ld + off + ((r & 15) << 6) + lane];
  float ss = v * v;
#pragma unroll
  for (int m = 32; m > 0; m >>= 1) ss += __shfl_xor(ss, m, 64);
  int h = r & 15, sIdx = (r >> 4) & 1023, b = r >> 14;
  float o = v * rsqrtf(ss + 1e-12f) * scale[(h << 6) + lane];
  dst[((((long)(b * 16 + h)) << 10) + sIdx) * 64 + lane] = f2b(o);
}

// V fp32 (row b*1024+s, col 2048+h*64+d of QKVF) -> V^T bf16 [z=(b,h)][128 pad][s]
__global__ __launch_bounds__(256)
void v_transpose(const float* __restrict__ vf, u16* __restrict__ vT) {
  int z = blockIdx.x, b = z >> 4, h = z & 15, s0 = blockIdx.y * 16;
  __shared__ u16 t[64][17];
  int si = threadIdx.x >> 6, d = threadIdx.x & 63;
#pragma unroll
  for (int j = 0; j < 4; j++) {
    int sl = j * 4 + si;
    t[d][sl] = f2b(vf[((long)(b << 10) + (s0 + sl)) * 3072 + 2048 + (h << 6) + d]);
  }
  __syncthreads();
  int d2 = threadIdx.x >> 2, sj = threadIdx.x & 3;
#pragma unroll
  for (int j = 0; j < 4; j++) {
    int sl = j * 4 + sj;
    vT[((long)(z * 128 + d2) << 10) + s0 + sl] = t[d2][sl];
  }
}

// causal row softmax: logits fp32 [z][i][j] (*10) -> P bf16, zeros for j>i
__global__ __launch_bounds__(256)
void softmax_kernel(const float* __restrict__ logits, u16* __restrict__ P) {
  int i = blockIdx.x, z = blockIdx.y, tid = threadIdx.x;
  long base = ((long)z << 20) + ((long)i << 10);
  int len = i + 1;
  float lv[4];
  float mx = -1e30f;
  int cnt = 0;
  for (int j = tid; j < len; j += 256) { float l = logits[base + j] * QK_SCALE_F; lv[cnt++] = l; mx = fmaxf(mx, l); }
  mx = wred_max(mx);
  __shared__ float red[4];
  int wave = tid >> 6, lane = tid & 63;
  if (lane == 0) red[wave] = mx;
  __syncthreads();
  mx = fmaxf(fmaxf(red[0], red[1]), fmaxf(red[2], red[3]));
  float s = 0.f;
  for (int c = 0; c < cnt; c++) { lv[c] = __expf(lv[c] - mx); s += lv[c]; }
  s = wred_sum(s);
  __syncthreads();
  if (lane == 0) red[wave] = s;
  __syncthreads();
  s = red[0] + red[1] + red[2] + red[3];
  float inv = 1.f / s;
  cnt = 0;
  for (int j = tid; j < len; j += 256) P[base + j] = f2b(lv[cnt++] * inv);
  for (int j = tid; j < 1024; j += 256) if (j >= len) P[base + j] = 0;
}

// pv fp32 [z=(b,h)][i][d] -> acat bf16 [b][i][h*64+d]
__global__ __launch_bounds__(256)
void attn_cat_kernel(const float* __restrict__ pv, u16* __restrict__ acat) {
  int blk = blockIdx.x; int b = blk >> 10, i = blk & 1023;
#pragma unroll
  for (int j = 0; j < 4; ++j) {
    int col = threadIdx.x + j * 256;
    int h = col >> 6, d = col & 63;
    float v = pv[(((long)(b * 16 + h)) << 16) + (i << 6) + d];
    acat[((long)blk << 10) + col] = f2b(v);
  }
}

// gate = softmax(h2 @ gate_w + gate_b), one row per block
__global__ __launch_bounds__(256)
void gate_kernel(const float* __restrict__ h2, const float* __restrict__ gw,
                 const float* __restrict__ gb, float* __restrict__ gate) {
  int row = blockIdx.x, tid = threadIdx.x;
  const float* hr = h2 + ((long)row << 10);
  float acc[8];
#pragma unroll
  for (int e = 0; e < 8; e++) acc[e] = 0.f;
  for (int d = tid; d < 1024; d += 256) {
    float hv = hr[d];
    const float4* wp = (const float4*)&gw[d * 8];
    float4 w0 = wp[0], w1v = wp[1];
    acc[0] += hv * w0.x;  acc[1] += hv * w0.y;  acc[2] += hv * w0.z;  acc[3] += hv * w0.w;
    acc[4] += hv * w1v.x; acc[5] += hv * w1v.y; acc[6] += hv * w1v.z; acc[7] += hv * w1v.w;
  }
  __shared__ float red[8][4];
  int wave = tid >> 6, lane = tid & 63;
#pragma unroll
  for (int e = 0; e < 8; e++) { float v = wred_sum(acc[e]); if (lane == 0) red[e][wave] = v; }
  __syncthreads();
  if (tid == 0) {
    float l[8]; float mx = -1e30f;
    for (int e = 0; e < 8; e++) { l[e] = red[e][0] + red[e][1] + red[e][2] + red[e][3] + gb[e]; mx = fmaxf(mx, l[e]); }
    float s = 0.f;
    for (int e = 0; e < 8; e++) { l[e] = __expf(l[e] - mx); s += l[e]; }
    float inv = 1.f / s;
    for (int e = 0; e < 8; e++) gate[row * 8 + e] = l[e] * inv;
  }
}

// moe init: moe[row][d] = sum_e gate[row][e] * b2[e][d]
__global__ __launch_bounds__(256)
void bias_moe_kernel(const float* __restrict__ gate, const float* __restrict__ b2, float* __restrict__ moe) {
  int row = blockIdx.x, tid = threadIdx.x;
  __shared__ float gs[8];
  if (tid < 8) gs[tid] = gate[row * 8 + tid];
  __syncthreads();
  for (int col = tid; col < 1024; col += 256) {
    float s = 0.f;
#pragma unroll
    for (int e = 0; e < 8; e++) s += gs[e] * b2[(e << 10) + col];
    moe[((long)row << 10) + col] = s;
  }
}

extern "C" void kernel_launch(void* const* d_in, const int* in_sizes, int n_in,
                              void* d_out, int out_size, void* d_ws, size_t ws_size,
                              hipStream_t stream) {
  const float* x   = (const float*)d_in[0];
  const float* lng = (const float*)d_in[1];
  const float* lnb = (const float*)d_in[2];
  const float* Wq  = (const float*)d_in[3];
  const float* Wk  = (const float*)d_in[4];
  const float* Wv  = (const float*)d_in[5];
  const float* qs  = (const float*)d_in[6];
  const float* ks  = (const float*)d_in[7];
  const float* Wo  = (const float*)d_in[8];
  const float* gw  = (const float*)d_in[9];
  const float* gb  = (const float*)d_in[10];
  const float* w1  = (const float*)d_in[11];
  const float* b1  = (const float*)d_in[12];
  const float* w2  = (const float*)d_in[13];
  const float* b2  = (const float*)d_in[14];
  float* out = (float*)d_out;

  char* base = (char*)d_ws;
  size_t off = 0;
  auto alloc = [&](size_t bytes) { void* p = base + off; off = (off + bytes + 255) & ~(size_t)255; return p; };

  u16*   W1T  = (u16*)alloc(8l * 1024 * 4096 * 2);   // [e][4096][1024] (B^T per expert)
  u16*   W2T  = (u16*)alloc(1024l * 32768 * 2);      // [1024][32768]
  u16*   WQKVT= (u16*)alloc(3072l * 1024 * 2);       // [3072][1024] (Wq;Wk;Wv B^T)
  u16*   WOT  = (u16*)alloc(1024l * 1024 * 2);
  u16*   HB   = (u16*)alloc(2048l * 1024 * 2);       // LN1 out bf16
  float* QKVF = (float*)alloc(2048l * 3072 * 4);     // fused QKV proj fp32
  u16*   QN   = (u16*)alloc(2048l * 1024 * 2);       // [b][h][s][d]
  u16*   KN   = (u16*)alloc(2048l * 1024 * 2);
  u16*   VT   = (u16*)alloc(32l * 128 * 1024 * 2);   // [z][128 pad][s]
  float* LOG  = (float*)alloc(32l * 1024 * 1024 * 4);// logits; region reused as HID bf16
  u16*   P    = (u16*)alloc(32l * 1024 * 1024 * 2);
  float* PV   = (float*)alloc(32l * 1024 * 64 * 4);
  u16*   ACAT = (u16*)alloc(2048l * 1024 * 2);
  float* APROJ= (float*)alloc(2048l * 1024 * 4);
  float* H2F  = (float*)alloc(2048l * 1024 * 4);
  u16*   H2B  = (u16*)alloc(2048l * 1024 * 2);
  float* GATE = (float*)alloc(2048l * 8 * 4);
  float* MOE  = (float*)alloc(2048l * 1024 * 4);
  u16*   HID  = (u16*)LOG;                           // [2048][32768] bf16, reuse

  if (off > ws_size) return;

  dim3 blk(256);

  // weight prep (B^T bf16)
  transpose_cast<<<dim3(32, 32, 1), blk, 0, stream>>>(Wq, WQKVT, 1024, 1024, 0, 0);
  transpose_cast<<<dim3(32, 32, 1), blk, 0, stream>>>(Wk, WQKVT + 1024l * 1024, 1024, 1024, 0, 0);
  transpose_cast<<<dim3(32, 32, 1), blk, 0, stream>>>(Wv, WQKVT + 2048l * 1024, 1024, 1024, 0, 0);
  transpose_cast<<<dim3(32, 32, 1), blk, 0, stream>>>(Wo, WOT, 1024, 1024, 0, 0);
  transpose_cast<<<dim3(128, 32, 8), blk, 0, stream>>>(w1, W1T, 1024, 4096, 1024l * 4096, 4096l * 1024);
  transpose_cast<<<dim3(32, 1024, 1), blk, 0, stream>>>(w2, W2T, 32768, 1024, 0, 0);

  // LN1 -> h (bf16)
  ln_kernel<<<2048, blk, 0, stream>>>(x, lng, lnb, nullptr, HB);

  // fused QKV projection: [2048][1024] x [3072][1024]^T -> [2048][3072]
  gemm_bt<0><<<dim3(24, 16, 1), blk, 0, stream>>>(HB, WQKVT, QKVF, 2048, 3072, 1024, 1024, 1024, 3072,
                                                  0, 0, 0, nullptr, 0, nullptr, 0);

  // l2norm + scale -> [b][h][s][d] bf16; V -> V^T
  l2norm_kernel<<<8192, blk, 0, stream>>>(QKVF, qs, QN, 3072, 0);
  l2norm_kernel<<<8192, blk, 0, stream>>>(QKVF, ks, KN, 3072, 1024);
  v_transpose<<<dim3(32, 64, 1), blk, 0, stream>>>(QKVF, VT);

  // attention: QK^T (causal skip) -> softmax -> PV
  gemm_bt<0><<<dim3(8, 8, 32), blk, 0, stream>>>(QN, KN, LOG, 1024, 1024, 64, 64, 64, 1024,
                                                 65536, 65536, 1048576, nullptr, 0, nullptr, 1);
  softmax_kernel<<<dim3(1024, 32, 1), blk, 0, stream>>>(LOG, P);
  gemm_bt<0><<<dim3(1, 8, 32), blk, 0, stream>>>(P, VT, PV, 1024, 64, 1024, 1024, 1024, 64,
                                                 1048576, 131072, 65536, nullptr, 0, nullptr, 0);
  attn_cat_kernel<<<2048, blk, 0, stream>>>(PV, ACAT);

  // output projection + LN2
  gemm_bt<0><<<dim3(8, 16, 1), blk, 0, stream>>>(ACAT, WOT, APROJ, 2048, 1024, 1024, 1024, 1024, 1024,
                                                 0, 0, 0, nullptr, 0, nullptr, 0);
  ln_kernel<<<2048, blk, 0, stream>>>(APROJ, lng, lnb, H2F, H2B);

  // MoE: gate, hid = gelu(h2@w1+b1)*gate  (bf16, [2048][32768])
  gate_kernel<<<2048, blk, 0, stream>>>(H2F, gw, gb, GATE);
  gemm_bt<2><<<dim3(32, 16, 8), blk, 0, stream>>>(H2B, W1T, HID, 2048, 4096, 1024, 1024, 1024, 32768,
                                                  0, 4096l * 1024, 4096, b1, 4096, GATE, 0);
  // combine: split-K over z (8 chunks of 4096), atomicAdd onto bias-preinit MOE
  bias_moe_kernel<<<2048, blk, 0, stream>>>(GATE, b2, MOE);
  gemm_bt<4><<<dim3(8, 16, 8), blk, 0, stream>>>(HID, W2T, MOE, 2048, 1024, 4096, 32768, 32768, 1024,
                                                 4096, 4096, 0, nullptr, 0, nullptr, 0);

  // final LN -> out
  ln_kernel<<<2048, blk, 0, stream>>>(MOE, lng, lnb, out, nullptr);
}

// Round 3
// 1012.258 us; speedup vs baseline: 1.5500x; 1.0402x over previous
//
#include <hip/hip_runtime.h>

typedef unsigned short u16;
typedef float f32x4 __attribute__((ext_vector_type(4)));
typedef short short8 __attribute__((ext_vector_type(8)));

#define QK_SCALE_F 10.0f

// async global->LDS, 16B per lane; LDS dest is wave-uniform base + lane*16
#define GLD_LDS(g, l) __builtin_amdgcn_global_load_lds( \
    (const __attribute__((address_space(1))) unsigned int*)(g), \
    (__attribute__((address_space(3))) unsigned int*)(l), 16, 0, 0)

__device__ __forceinline__ u16 f2b(float f) {
  union { float f; unsigned u; } c; c.f = f;
  return (u16)((c.u + 0x7fffu + ((c.u >> 16) & 1u)) >> 16);
}

__device__ __forceinline__ float wred_sum(float v) {
#pragma unroll
  for (int m = 32; m > 0; m >>= 1) v += __shfl_xor(v, m, 64);
  return v;
}
__device__ __forceinline__ float wred_max(float v) {
#pragma unroll
  for (int m = 32; m > 0; m >>= 1) v = fmaxf(v, __shfl_xor(v, m, 64));
  return v;
}

// ---------------------------------------------------------------------------
// Generic bf16 MFMA GEMM:  C[M,N] = A[M,K] * B^T[N,K]   (both bf16, row-major)
// 128x128 tile, BK=64, 256 threads = 4 waves (2x2), each wave 64x64 via 4x4
// v_mfma_f32_16x16x32_bf16 fragments.
// 2-phase pipelined (T3-minimal): double-buffered LDS; per tile we drain the
// previous stage at the barrier, then ISSUE next-tile global_load_lds, then
// compute the current tile -> loads overlap the whole compute phase.
// Staging: global_load_lds dwordx4, LINEAR LDS dest; XOR swizzle applied to
// the per-lane GLOBAL source column so the swizzled b128 read path (0 bank
// conflicts, verified R1/R2) sees identical LDS content (rule 21).
// EPI 0: C fp32 = acc
// EPI 2: C bf16 = gelu(acc + P1[z][col]) * P2[row][z]      (hid GEMM)
//        gelu via exact sigmoid form: 0.5t(1+tanh(z)) == t*sigma(2z)
// ---------------------------------------------------------------------------
#define BM 128
#define BN 128
#define BKK 64

template<int EPI>
__global__ __launch_bounds__(256)
void gemm_bt(const u16* __restrict__ A, const u16* __restrict__ B, void* __restrict__ Cv,
             int M, int N, int K, int lda, int ldb, int ldc,
             long zA, long zB, long zC,
             const float* __restrict__ P1, long zP1, const float* __restrict__ P2,
             int causal) {
  int z = blockIdx.z;
  int row0 = blockIdx.y * BM;
  int col0 = blockIdx.x * BN;
  if (causal && col0 > row0 + (BM - 1)) return;  // tile fully above causal diag
  A += zA * z; B += zB * z;
  int tid = threadIdx.x;
  int wave = tid >> 6, lane = tid & 63;
  int wm = wave >> 1, wn = wave & 1;

  __shared__ __align__(16) u16 lA[2][BM * BKK];
  __shared__ __align__(16) u16 lB[2][BN * BKK];

  f32x4 acc[4][4];
  f32x4 zf = {0.f, 0.f, 0.f, 0.f};
#pragma unroll
  for (int i = 0; i < 4; i++)
#pragma unroll
    for (int j = 0; j < 4; j++) acc[i][j] = zf;

  // per-lane staging geometry (constant across K loop)
  int l3 = lane >> 3;                       // 0..7  == row-within-8 == r&7
  int scol = ((lane & 7) ^ l3) << 3;        // swizzled source column (elements)
  long aoff[4], boff[4];
  int cbase[4];
#pragma unroll
  for (int i = 0; i < 4; i++) {
    int c = (wave << 2) + i;                // 1KB chunk id 0..15
    int r = (c << 3) + l3;                  // tile row 0..127
    aoff[i] = (long)(row0 + r) * lda + scol;
    boff[i] = (long)(col0 + r) * ldb + scol;
    cbase[i] = c << 10;                     // LDS byte offset of chunk
  }

  auto stage = [&](int buf, int k0) {
#pragma unroll
    for (int i = 0; i < 4; i++) {
      GLD_LDS(A + aoff[i] + k0, (char*)lA[buf] + cbase[i]);
      GLD_LDS(B + boff[i] + k0, (char*)lB[buf] + cbase[i]);
    }
  };

  int nt = K / BKK;
  stage(0, 0);
  int cur = 0;
  for (int t = 0; t < nt; ++t) {
    __syncthreads();                         // drains vmcnt: buf[cur] ready
    if (t + 1 < nt) stage(cur ^ 1, (t + 1) * BKK);
    const char* pA = (const char*)lA[cur];
    const char* pB = (const char*)lB[cur];
#pragma unroll
    for (int kk = 0; kk < 2; kk++) {
      short8 af[4], bfr[4];
      int cb = (kk << 6) | ((lane >> 4) << 4);
#pragma unroll
      for (int mi = 0; mi < 4; mi++) {
        int R = (wm << 6) + (mi << 4) + (lane & 15);
        af[mi] = *(const short8*)(pA + ((R << 7) | (cb ^ ((R & 7) << 4))));
      }
#pragma unroll
      for (int nj = 0; nj < 4; nj++) {
        int R = (wn << 6) + (nj << 4) + (lane & 15);
        bfr[nj] = *(const short8*)(pB + ((R << 7) | (cb ^ ((R & 7) << 4))));
      }
#pragma unroll
      for (int mi = 0; mi < 4; mi++)
#pragma unroll
        for (int nj = 0; nj < 4; nj++)
          acc[mi][nj] = __builtin_amdgcn_mfma_f32_16x16x32_bf16(af[mi], bfr[nj], acc[mi][nj], 0, 0, 0);
    }
    cur ^= 1;
  }

#pragma unroll
  for (int mi = 0; mi < 4; mi++) {
#pragma unroll
    for (int nj = 0; nj < 4; nj++) {
#pragma unroll
      for (int rr = 0; rr < 4; rr++) {
        int row = row0 + (wm << 6) + (mi << 4) + ((lane >> 4) << 2) + rr;
        int col = col0 + (wn << 6) + (nj << 4) + (lane & 15);
        if (col < N) {
          float v = acc[mi][nj][rr];
          long cidx = zC * z + (long)row * ldc + col;
          if (EPI == 0) {
            ((float*)Cv)[cidx] = v;
          } else if (EPI == 2) {
            float t = v + P1[zP1 * z + col];
            float zz = 1.5957691216f * (t + 0.044715f * t * t * t);
            float gl = t / (1.f + __expf(-zz));
            ((u16*)Cv)[cidx] = f2b(gl * P2[((long)row << 3) + z]);
          }
        }
      }
    }
  }
}

// fp32 [R][C] -> bf16 [C][R] tiled transpose-cast (weights -> B^T form)
__global__ __launch_bounds__(256)
void transpose_cast(const float* __restrict__ src, u16* __restrict__ dst,
                    int R, int C, long sz, long dz) {
  int z = blockIdx.z;
  src += sz * z; dst += dz * z;
  __shared__ float t[32][33];
  int c0 = blockIdx.x * 32, r0 = blockIdx.y * 32;
  int tx = threadIdx.x & 31, ty = threadIdx.x >> 5;
#pragma unroll
  for (int j = 0; j < 4; j++) {
    int r = ty + j * 8;
    t[r][tx] = src[(long)(r0 + r) * C + c0 + tx];
  }
  __syncthreads();
#pragma unroll
  for (int j = 0; j < 4; j++) {
    int r = ty + j * 8;
    dst[(long)(c0 + r) * R + r0 + tx] = f2b(t[tx][r]);
  }
}

// LayerNorm over D=1024, one row per block; optional fp32 and bf16 outputs
__global__ __launch_bounds__(256)
void ln_kernel(const float* __restrict__ x, const float* __restrict__ g,
               const float* __restrict__ b, float* __restrict__ yf, u16* __restrict__ yb) {
  int tid = threadIdx.x;
  long base = (long)blockIdx.x << 10;
  float4 v = *(const float4*)&x[base + tid * 4];
  float s = v.x + v.y + v.z + v.w;
  float q = v.x * v.x + v.y * v.y + v.z * v.z + v.w * v.w;
  s = wred_sum(s); q = wred_sum(q);
  __shared__ float2 red[4];
  int wave = tid >> 6, lane = tid & 63;
  if (lane == 0) red[wave] = make_float2(s, q);
  __syncthreads();
  float S1 = red[0].x + red[1].x + red[2].x + red[3].x;
  float S2 = red[0].y + red[1].y + red[2].y + red[3].y;
  float mu = S1 * (1.f / 1024.f);
  float var = S2 * (1.f / 1024.f) - mu * mu;
  float rs = rsqrtf(var + 1e-5f);
  float4 gv = *(const float4*)&g[tid * 4];
  float4 bv = *(const float4*)&b[tid * 4];
  float4 o;
  o.x = (v.x - mu) * rs * gv.x + bv.x;
  o.y = (v.y - mu) * rs * gv.y + bv.y;
  o.z = (v.z - mu) * rs * gv.z + bv.z;
  o.w = (v.w - mu) * rs * gv.w + bv.w;
  if (yf) *(float4*)&yf[base + tid * 4] = o;
  if (yb) {
    ushort4 ob; ob.x = f2b(o.x); ob.y = f2b(o.y); ob.z = f2b(o.z); ob.w = f2b(o.w);
    *(ushort4*)&yb[base + tid * 4] = ob;
  }
}

// final fused kernel: sum 8 split-K slices + sum_e gate[e]*b2[e][col], then LN
__global__ __launch_bounds__(256)
void ln_reduce8(const float* __restrict__ sl, const float* __restrict__ gate,
                const float* __restrict__ b2, const float* __restrict__ g,
                const float* __restrict__ b, float* __restrict__ out) {
  int row = blockIdx.x, tid = threadIdx.x;
  __shared__ float gs[8];
  if (tid < 8) gs[tid] = gate[(row << 3) + tid];
  __syncthreads();
  long rbase = (long)row << 10;
  int col = tid << 2;
  float4 a = {0.f, 0.f, 0.f, 0.f};
#pragma unroll
  for (int s = 0; s < 8; s++) {
    float4 v = *(const float4*)&sl[(long)s * (2048l * 1024) + rbase + col];
    a.x += v.x; a.y += v.y; a.z += v.z; a.w += v.w;
  }
#pragma unroll
  for (int e = 0; e < 8; e++) {
    float4 bv = *(const float4*)&b2[(e << 10) + col];
    float ge = gs[e];
    a.x += ge * bv.x; a.y += ge * bv.y; a.z += ge * bv.z; a.w += ge * bv.w;
  }
  float s1 = a.x + a.y + a.z + a.w;
  float q = a.x * a.x + a.y * a.y + a.z * a.z + a.w * a.w;
  s1 = wred_sum(s1); q = wred_sum(q);
  __shared__ float2 red[4];
  int wave = tid >> 6, lane = tid & 63;
  if (lane == 0) red[wave] = make_float2(s1, q);
  __syncthreads();
  float S1 = red[0].x + red[1].x + red[2].x + red[3].x;
  float S2 = red[0].y + red[1].y + red[2].y + red[3].y;
  float mu = S1 * (1.f / 1024.f);
  float var = S2 * (1.f / 1024.f) - mu * mu;
  float rs = rsqrtf(var + 1e-5f);
  float4 gv = *(const float4*)&g[col];
  float4 bv = *(const float4*)&b[col];
  float4 o;
  o.x = (a.x - mu) * rs * gv.x + bv.x;
  o.y = (a.y - mu) * rs * gv.y + bv.y;
  o.z = (a.z - mu) * rs * gv.z + bv.z;
  o.w = (a.w - mu) * rs * gv.w + bv.w;
  *(float4*)&out[rbase + col] = o;
}

// l2norm+scale over DH=64 per (b,s,h); src fp32 row (b*1024+s), col off+h*64+d
// -> dst [b][h][s][d] bf16
__global__ __launch_bounds__(256)
void l2norm_kernel(const float* __restrict__ src, const float* __restrict__ scale,
                   u16* __restrict__ dst, int ld, int off) {
  int r = blockIdx.x * 4 + (threadIdx.x >> 6);
  int lane = threadIdx.x & 63;
  float v = src[(long)(r >> 4) * ld + off + ((r & 15) << 6) + lane];
  float ss = v * v;
#pragma unroll
  for (int m = 32; m > 0; m >>= 1) ss += __shfl_xor(ss, m, 64);
  int h = r & 15, sIdx = (r >> 4) & 1023, b = r >> 14;
  float o = v * rsqrtf(ss + 1e-12f) * scale[(h << 6) + lane];
  dst[((((long)(b * 16 + h)) << 10) + sIdx) * 64 + lane] = f2b(o);
}

// V fp32 (row b*1024+s, col 2048+h*64+d of QKVF) -> V^T bf16 [z=(b,h)][128 pad][s]
__global__ __launch_bounds__(256)
void v_transpose(const float* __restrict__ vf, u16* __restrict__ vT) {
  int z = blockIdx.x, b = z >> 4, h = z & 15, s0 = blockIdx.y * 16;
  __shared__ u16 t[64][17];
  int si = threadIdx.x >> 6, d = threadIdx.x & 63;
#pragma unroll
  for (int j = 0; j < 4; j++) {
    int sl = j * 4 + si;
    t[d][sl] = f2b(vf[((long)(b << 10) + (s0 + sl)) * 3072 + 2048 + (h << 6) + d]);
  }
  __syncthreads();
  int d2 = threadIdx.x >> 2, sj = threadIdx.x & 3;
#pragma unroll
  for (int j = 0; j < 4; j++) {
    int sl = j * 4 + sj;
    vT[((long)(z * 128 + d2) << 10) + s0 + sl] = t[d2][sl];
  }
}

// causal row softmax: logits fp32 [z][i][j] (*10) -> P bf16, zeros for j>i
__global__ __launch_bounds__(256)
void softmax_kernel(const float* __restrict__ logits, u16* __restrict__ P) {
  int i = blockIdx.x, z = blockIdx.y, tid = threadIdx.x;
  long base = ((long)z << 20) + ((long)i << 10);
  int len = i + 1;
  float lv[4];
  float mx = -1e30f;
  int cnt = 0;
  for (int j = tid; j < len; j += 256) { float l = logits[base + j] * QK_SCALE_F; lv[cnt++] = l; mx = fmaxf(mx, l); }
  mx = wred_max(mx);
  __shared__ float red[4];
  int wave = tid >> 6, lane = tid & 63;
  if (lane == 0) red[wave] = mx;
  __syncthreads();
  mx = fmaxf(fmaxf(red[0], red[1]), fmaxf(red[2], red[3]));
  float s = 0.f;
  for (int c = 0; c < cnt; c++) { lv[c] = __expf(lv[c] - mx); s += lv[c]; }
  s = wred_sum(s);
  __syncthreads();
  if (lane == 0) red[wave] = s;
  __syncthreads();
  s = red[0] + red[1] + red[2] + red[3];
  float inv = 1.f / s;
  cnt = 0;
  for (int j = tid; j < len; j += 256) P[base + j] = f2b(lv[cnt++] * inv);
  for (int j = tid; j < 1024; j += 256) if (j >= len) P[base + j] = 0;
}

// pv fp32 [z=(b,h)][i][d] -> acat bf16 [b][i][h*64+d]
__global__ __launch_bounds__(256)
void attn_cat_kernel(const float* __restrict__ pv, u16* __restrict__ acat) {
  int blk = blockIdx.x; int b = blk >> 10, i = blk & 1023;
#pragma unroll
  for (int j = 0; j < 4; ++j) {
    int col = threadIdx.x + j * 256;
    int h = col >> 6, d = col & 63;
    float v = pv[(((long)(b * 16 + h)) << 16) + (i << 6) + d];
    acat[((long)blk << 10) + col] = f2b(v);
  }
}

// gate = softmax(h2 @ gate_w + gate_b), one row per block
__global__ __launch_bounds__(256)
void gate_kernel(const float* __restrict__ h2, const float* __restrict__ gw,
                 const float* __restrict__ gb, float* __restrict__ gate) {
  int row = blockIdx.x, tid = threadIdx.x;
  const float* hr = h2 + ((long)row << 10);
  float acc[8];
#pragma unroll
  for (int e = 0; e < 8; e++) acc[e] = 0.f;
  for (int d = tid; d < 1024; d += 256) {
    float hv = hr[d];
    const float4* wp = (const float4*)&gw[d * 8];
    float4 w0 = wp[0], w1v = wp[1];
    acc[0] += hv * w0.x;  acc[1] += hv * w0.y;  acc[2] += hv * w0.z;  acc[3] += hv * w0.w;
    acc[4] += hv * w1v.x; acc[5] += hv * w1v.y; acc[6] += hv * w1v.z; acc[7] += hv * w1v.w;
  }
  __shared__ float red[8][4];
  int wave = tid >> 6, lane = tid & 63;
#pragma unroll
  for (int e = 0; e < 8; e++) { float v = wred_sum(acc[e]); if (lane == 0) red[e][wave] = v; }
  __syncthreads();
  if (tid == 0) {
    float l[8]; float mx = -1e30f;
    for (int e = 0; e < 8; e++) { l[e] = red[e][0] + red[e][1] + red[e][2] + red[e][3] + gb[e]; mx = fmaxf(mx, l[e]); }
    float s = 0.f;
    for (int e = 0; e < 8; e++) { l[e] = __expf(l[e] - mx); s += l[e]; }
    float inv = 1.f / s;
    for (int e = 0; e < 8; e++) gate[row * 8 + e] = l[e] * inv;
  }
}

extern "C" void kernel_launch(void* const* d_in, const int* in_sizes, int n_in,
                              void* d_out, int out_size, void* d_ws, size_t ws_size,
                              hipStream_t stream) {
  const float* x   = (const float*)d_in[0];
  const float* lng = (const float*)d_in[1];
  const float* lnb = (const float*)d_in[2];
  const float* Wq  = (const float*)d_in[3];
  const float* Wk  = (const float*)d_in[4];
  const float* Wv  = (const float*)d_in[5];
  const float* qs  = (const float*)d_in[6];
  const float* ks  = (const float*)d_in[7];
  const float* Wo  = (const float*)d_in[8];
  const float* gw  = (const float*)d_in[9];
  const float* gb  = (const float*)d_in[10];
  const float* w1  = (const float*)d_in[11];
  const float* b1  = (const float*)d_in[12];
  const float* w2  = (const float*)d_in[13];
  const float* b2  = (const float*)d_in[14];
  float* out = (float*)d_out;

  char* base = (char*)d_ws;
  size_t off = 0;
  auto alloc = [&](size_t bytes) { void* p = base + off; off = (off + bytes + 255) & ~(size_t)255; return p; };

  u16*   W1T  = (u16*)alloc(8l * 1024 * 4096 * 2);   // [e][4096][1024] (B^T per expert)
  u16*   W2T  = (u16*)alloc(1024l * 32768 * 2);      // [1024][32768]
  u16*   WQKVT= (u16*)alloc(3072l * 1024 * 2);       // [3072][1024] (Wq;Wk;Wv B^T)
  u16*   WOT  = (u16*)alloc(1024l * 1024 * 2);
  u16*   HB   = (u16*)alloc(2048l * 1024 * 2);       // LN1 out bf16
  float* QKVF = (float*)alloc(2048l * 3072 * 4);     // fused QKV proj fp32
  u16*   QN   = (u16*)alloc(2048l * 1024 * 2);       // [b][h][s][d]
  u16*   KN   = (u16*)alloc(2048l * 1024 * 2);
  u16*   VT   = (u16*)alloc(32l * 128 * 1024 * 2);   // [z][128 pad][s]
  float* LOG  = (float*)alloc(32l * 1024 * 1024 * 4);// logits; region reused as HID bf16
  u16*   P    = (u16*)alloc(32l * 1024 * 1024 * 2);  // attn probs; reused as MOE8 slices
  float* PV   = (float*)alloc(32l * 1024 * 64 * 4);
  u16*   ACAT = (u16*)alloc(2048l * 1024 * 2);
  float* APROJ= (float*)alloc(2048l * 1024 * 4);
  float* H2F  = (float*)alloc(2048l * 1024 * 4);
  u16*   H2B  = (u16*)alloc(2048l * 1024 * 2);
  float* GATE = (float*)alloc(2048l * 8 * 4);
  u16*   HID  = (u16*)LOG;                           // [2048][32768] bf16, reuse
  float* MOE8 = (float*)P;                           // [8][2048][1024] fp32 split-K slices, reuse

  if (off > ws_size) return;

  dim3 blk(256);

  // weight prep (B^T bf16)
  transpose_cast<<<dim3(32, 32, 1), blk, 0, stream>>>(Wq, WQKVT, 1024, 1024, 0, 0);
  transpose_cast<<<dim3(32, 32, 1), blk, 0, stream>>>(Wk, WQKVT + 1024l * 1024, 1024, 1024, 0, 0);
  transpose_cast<<<dim3(32, 32, 1), blk, 0, stream>>>(Wv, WQKVT + 2048l * 1024, 1024, 1024, 0, 0);
  transpose_cast<<<dim3(32, 32, 1), blk, 0, stream>>>(Wo, WOT, 1024, 1024, 0, 0);
  transpose_cast<<<dim3(128, 32, 8), blk, 0, stream>>>(w1, W1T, 1024, 4096, 1024l * 4096, 4096l * 1024);
  transpose_cast<<<dim3(32, 1024, 1), blk, 0, stream>>>(w2, W2T, 32768, 1024, 0, 0);

  // LN1 -> h (bf16)
  ln_kernel<<<2048, blk, 0, stream>>>(x, lng, lnb, nullptr, HB);

  // fused QKV projection: [2048][1024] x [3072][1024]^T -> [2048][3072]
  gemm_bt<0><<<dim3(24, 16, 1), blk, 0, stream>>>(HB, WQKVT, QKVF, 2048, 3072, 1024, 1024, 1024, 3072,
                                                  0, 0, 0, nullptr, 0, nullptr, 0);

  // l2norm + scale -> [b][h][s][d] bf16; V -> V^T
  l2norm_kernel<<<8192, blk, 0, stream>>>(QKVF, qs, QN, 3072, 0);
  l2norm_kernel<<<8192, blk, 0, stream>>>(QKVF, ks, KN, 3072, 1024);
  v_transpose<<<dim3(32, 64, 1), blk, 0, stream>>>(QKVF, VT);

  // attention: QK^T (causal skip) -> softmax -> PV
  gemm_bt<0><<<dim3(8, 8, 32), blk, 0, stream>>>(QN, KN, LOG, 1024, 1024, 64, 64, 64, 1024,
                                                 65536, 65536, 1048576, nullptr, 0, nullptr, 1);
  softmax_kernel<<<dim3(1024, 32, 1), blk, 0, stream>>>(LOG, P);
  gemm_bt<0><<<dim3(1, 8, 32), blk, 0, stream>>>(P, VT, PV, 1024, 64, 1024, 1024, 1024, 64,
                                                 1048576, 131072, 65536, nullptr, 0, nullptr, 0);
  attn_cat_kernel<<<2048, blk, 0, stream>>>(PV, ACAT);

  // output projection + LN2
  gemm_bt<0><<<dim3(8, 16, 1), blk, 0, stream>>>(ACAT, WOT, APROJ, 2048, 1024, 1024, 1024, 1024, 1024,
                                                 0, 0, 0, nullptr, 0, nullptr, 0);
  ln_kernel<<<2048, blk, 0, stream>>>(APROJ, lng, lnb, H2F, H2B);

  // MoE: gate, hid = gelu(h2@w1+b1)*gate  (bf16, [2048][32768])
  gate_kernel<<<2048, blk, 0, stream>>>(H2F, gw, gb, GATE);
  gemm_bt<2><<<dim3(32, 16, 8), blk, 0, stream>>>(H2B, W1T, HID, 2048, 4096, 1024, 1024, 1024, 32768,
                                                  0, 4096l * 1024, 4096, b1, 4096, GATE, 0);
  // combine: split-K over z (8 chunks of 4096) -> fp32 slices (atomic-free)
  gemm_bt<0><<<dim3(8, 16, 8), blk, 0, stream>>>(HID, W2T, MOE8, 2048, 1024, 4096, 32768, 32768, 1024,
                                                 4096, 4096, 2048l * 1024, nullptr, 0, nullptr, 0);

  // final: slice-sum + gate*b2 bias + LN -> out
  ln_reduce8<<<2048, blk, 0, stream>>>(MOE8, GATE, b2, lng, lnb, out);
}